// Round 1
// baseline (256.424 us; speedup 1.0000x reference)
//
#include <hip/hip_runtime.h>
#include <stdint.h>

#define N_ANCH 36864
#define KCAND  4096
#define NSEL   300
#define NGT    64
#define NBATCH 16
#define SCORE_THRESH 0.908f

__device__ __forceinline__ float clip01(float v) { return fminf(fmaxf(v, 0.0f), 1.0f); }

// IoU with the exact op order of the reference (a = earlier/selected box)
__device__ __forceinline__ float iou_pair(const float* a, const float* b) {
    float y1 = fmaxf(a[0], b[0]);
    float x1 = fmaxf(a[1], b[1]);
    float y2 = fminf(a[2], b[2]);
    float x2 = fminf(a[3], b[3]);
    float ih = fmaxf(y2 - y1, 0.0f);
    float iw = fmaxf(x2 - x1, 0.0f);
    float inter = ih * iw;
    float aa = (a[2] - a[0]) * (a[3] - a[1]);
    float ab = (b[2] - b[0]) * (b[3] - b[1]);
    return inter / (aa + ab - inter + 1e-7f);
}

__global__ __launch_bounds__(1024)
void roi_bbox_kernel(const float* __restrict__ deltas,
                     const float* __restrict__ labels,
                     const float* __restrict__ anchors,
                     const float* __restrict__ gt,
                     float* __restrict__ out)
{
    __shared__ unsigned long long s_keys[KCAND];   // 32 KB
    __shared__ float s_acc[NSEL][4];               // accepted raw (unclipped) boxes
    __shared__ float s_cbox[64][4];                // current chunk boxes
    __shared__ unsigned int s_pre[64];             // suppressed-by-accepted flags
    __shared__ unsigned int s_gmlo[64];            // intra-chunk mask lo
    __shared__ unsigned int s_gmhi[64];            // intra-chunk mask hi
    __shared__ int s_cnt;
    __shared__ int s_accCount;
    __shared__ float s_merged[NSEL];
    __shared__ int   s_gtbest[NSEL];
    __shared__ float s_gt[NGT][4];
    __shared__ int   s_selidx[64];

    const int b = blockIdx.x;
    const int tid = threadIdx.x;
    const float*  sc    = labels + (size_t)b * N_ANCH;
    const float4* anch4 = (const float4*)(anchors + (size_t)b * N_ANCH * 4);
    const float4* del4  = (const float4*)(deltas  + (size_t)b * N_ANCH * 4);
    const float4* gt4   = (const float4*)(gt + (size_t)b * NGT * 4);

    if (tid == 0) { s_cnt = 0; s_accCount = 0; }
    __syncthreads();

    // ---- Phase A: threshold-compact top candidates ----
    for (int i = tid; i < N_ANCH; i += 1024) {
        float s = sc[i];
        if (s > SCORE_THRESH) {
            int p = atomicAdd(&s_cnt, 1);
            if (p < KCAND) {
                // key: score bits desc, then index asc (jnp argmax/stable-sort tie-break)
                s_keys[p] = ((unsigned long long)__float_as_uint(s) << 32)
                          | (unsigned long long)(0xFFFFFFFFu - (unsigned)i);
            }
        }
    }
    __syncthreads();
    int M = s_cnt; if (M > KCAND) M = KCAND;
    for (int i = tid; i < KCAND; i += 1024) if (i >= M) s_keys[i] = 0ull;
    __syncthreads();

    // ---- bitonic sort, descending ----
    for (int k = 2; k <= KCAND; k <<= 1) {
        for (int j = k >> 1; j > 0; j >>= 1) {
            #pragma unroll
            for (int s = 0; s < KCAND / 1024; ++s) {
                int i = tid + (s << 10);
                int l = i ^ j;
                if (l > i) {
                    unsigned long long a = s_keys[i];
                    unsigned long long c = s_keys[l];
                    bool up = ((i & k) == 0);           // descending overall
                    if (up ? (a < c) : (a > c)) { s_keys[i] = c; s_keys[l] = a; }
                }
            }
            __syncthreads();
        }
    }

    // ---- Phase B: greedy NMS over sorted candidates, 64-wide chunks ----
    int accCount = 0;
    for (int start = 0; start < M && accCount < NSEL; start += 64) {
        int C = M - start; if (C > 64) C = 64;
        if (tid < 64) {
            s_pre[tid]  = (tid < C) ? 0u : 1u;
            s_gmlo[tid] = 0u;
            s_gmhi[tid] = 0u;
        }
        if (tid < C) {
            unsigned long long key = s_keys[start + tid];
            int idx = (int)(0xFFFFFFFFu - (unsigned)(key & 0xFFFFFFFFull));
            float4 a4 = anch4[idx];
            float4 d4 = del4[idx];
            float ah = a4.z - a4.x, aw = a4.w - a4.y;
            float acy = a4.x + 0.5f * ah, acx = a4.y + 0.5f * aw;
            float h = expf(d4.z) * ah, w = expf(d4.w) * aw;
            float cy = d4.x * ah + acy, cx = d4.y * aw + acx;
            float y1 = cy - 0.5f * h, x1 = cx - 0.5f * w;
            s_cbox[tid][0] = y1; s_cbox[tid][1] = x1;
            s_cbox[tid][2] = y1 + h; s_cbox[tid][3] = x1 + w;
        }
        __syncthreads();

        int c = tid & 63, sl = tid >> 6;   // 16 thread-slices per candidate
        if (c < C) {
            for (int a = sl; a < accCount; a += 16) {
                if (iou_pair(s_acc[a], s_cbox[c]) >= 0.5f) { atomicOr(&s_pre[c], 1u); break; }
            }
            unsigned int mlo = 0u, mhi = 0u;
            for (int j = sl; j < c; j += 16) {
                if (iou_pair(s_cbox[j], s_cbox[c]) >= 0.5f) {
                    if (j < 32) mlo |= 1u << j; else mhi |= 1u << (j - 32);
                }
            }
            if (mlo) atomicOr(&s_gmlo[c], mlo);
            if (mhi) atomicOr(&s_gmhi[c], mhi);
        }
        __syncthreads();

        // wave-0 serial resolution of intra-chunk dependencies (all in registers/shfl)
        if (tid < 64) {
            unsigned long long mymask = ((unsigned long long)s_gmhi[tid] << 32) | s_gmlo[tid];
            bool mypre = (s_pre[tid] != 0u);
            unsigned long long dead = __ballot(mypre);
            unsigned long long accbits = 0ull;
            for (int l = 0; l < C; ++l) {
                unsigned long long ml = __shfl(mymask, l);
                if (!((dead >> l) & 1ull) && (ml & accbits) == 0ull)
                    accbits |= (1ull << l);
            }
            int room  = NSEL - accCount;
            int total = __popcll(accbits);
            if ((accbits >> tid) & 1ull) {
                int rank = __popcll(accbits & ((1ull << tid) - 1ull));
                if (rank < room) {
                    int pos = accCount + rank;
                    s_acc[pos][0] = s_cbox[tid][0];
                    s_acc[pos][1] = s_cbox[tid][1];
                    s_acc[pos][2] = s_cbox[tid][2];
                    s_acc[pos][3] = s_cbox[tid][3];
                }
            }
            if (tid == 0) s_accCount = accCount + (total < room ? total : room);
        }
        __syncthreads();
        accCount = s_accCount;
    }

    // ---- Phase C: select_rois ----
    if (tid < NGT) {
        float4 g = gt4[tid];
        s_gt[tid][0] = g.x; s_gt[tid][1] = g.y; s_gt[tid][2] = g.z; s_gt[tid][3] = g.w;
    }
    __syncthreads();

    if (tid < NSEL) {
        float bx0, bx1, bx2, bx3;
        if (tid < accCount) {
            bx0 = clip01(s_acc[tid][0]); bx1 = clip01(s_acc[tid][1]);
            bx2 = clip01(s_acc[tid][2]); bx3 = clip01(s_acc[tid][3]);
        } else { bx0 = bx1 = bx2 = bx3 = 0.0f; }
        float aa = (bx2 - bx0) * (bx3 - bx1);
        float best = -1e38f; int bi = 0;
        for (int g = 0; g < NGT; ++g) {
            float y1 = fmaxf(bx0, s_gt[g][0]);
            float x1 = fmaxf(bx1, s_gt[g][1]);
            float y2 = fminf(bx2, s_gt[g][2]);
            float x2 = fminf(bx3, s_gt[g][3]);
            float ih = fmaxf(y2 - y1, 0.0f);
            float iw = fmaxf(x2 - x1, 0.0f);
            float inter = ih * iw;
            float ab = (s_gt[g][2] - s_gt[g][0]) * (s_gt[g][3] - s_gt[g][1]);
            float iou = inter / (aa + ab - inter + 1e-7f);
            if (iou > best) { best = iou; bi = g; }   // strict > : first-occurrence argmax
        }
        s_merged[tid] = best;
        s_gtbest[tid] = bi;
    }
    __syncthreads();

    // stable top-64 (max value, ties -> smallest index) == argsort(-merged)[:64]
    if (tid < 64) {
        float v[5]; int idp[5];
        #pragma unroll
        for (int s = 0; s < 5; ++s) {
            int i = tid + (s << 6);
            if (i < NSEL) { v[s] = s_merged[i]; idp[s] = i; }
            else          { v[s] = -1.0f;       idp[s] = 1 << 30; }
        }
        for (int r = 0; r < 64; ++r) {
            float bv = v[0]; int bidx = idp[0];
            #pragma unroll
            for (int s = 1; s < 5; ++s)
                if (v[s] > bv || (v[s] == bv && idp[s] < bidx)) { bv = v[s]; bidx = idp[s]; }
            for (int off = 32; off > 0; off >>= 1) {
                float ov = __shfl_xor(bv, off);
                int   oi = __shfl_xor(bidx, off);
                if (ov > bv || (ov == bv && oi < bidx)) { bv = ov; bidx = oi; }
            }
            if ((bidx & 63) == tid) v[bidx >> 6] = -2.0f;  // remove (merged >= 0 always)
            if (tid == 0) s_selidx[r] = bidx;
        }
    }
    __syncthreads();

    // ---- outputs ----
    float* outIdx = out + (size_t)NBATCH * 128 * 4;   // 8192 floats of roi boxes first
    if (tid < 256) {
        int r = tid >> 2, cc = tid & 3;
        int i = s_selidx[r];
        float val = (i < accCount) ? clip01(s_acc[i][cc]) : 0.0f;
        out[((size_t)b * 128 + r) * 4 + cc] = val;
    } else if (tid < 512) {
        int j = tid - 256;
        out[((size_t)b * 128 + 64) * 4 + j] = 0.0f;   // TOTAL_NEG zero boxes
    } else if (tid < 576) {
        int r = tid - 512;
        outIdx[b * 64 + r] = (float)s_gtbest[s_selidx[r]];
    }
}

extern "C" void kernel_launch(void* const* d_in, const int* in_sizes, int n_in,
                              void* d_out, int out_size, void* d_ws, size_t ws_size,
                              hipStream_t stream) {
    const float* deltas  = (const float*)d_in[0];
    const float* labels  = (const float*)d_in[1];
    const float* anchors = (const float*)d_in[2];
    const float* gt      = (const float*)d_in[3];
    float* out = (float*)d_out;
    roi_bbox_kernel<<<NBATCH, 1024, 0, stream>>>(deltas, labels, anchors, gt, out);
}

// Round 2
// 212.702 us; speedup vs baseline: 1.2056x; 1.2056x over previous
//
#include <hip/hip_runtime.h>
#include <stdint.h>

#define N_ANCH 36864
#define KCAND  4096
#define NSEL   300
#define NGT    64
#define NBATCH 16
#define SCORE_THRESH 0.908f

typedef unsigned long long u64;

__device__ __forceinline__ float clip01(float v) { return fminf(fmaxf(v, 0.0f), 1.0f); }

// IoU with the exact op order of the reference (a = earlier/selected box)
__device__ __forceinline__ float iou4(const float4 a, const float4 b) {
    float y1 = fmaxf(a.x, b.x);
    float x1 = fmaxf(a.y, b.y);
    float y2 = fminf(a.z, b.z);
    float x2 = fminf(a.w, b.w);
    float ih = fmaxf(y2 - y1, 0.0f);
    float iw = fmaxf(x2 - x1, 0.0f);
    float inter = ih * iw;
    float aa = (a.z - a.x) * (a.w - a.y);
    float ab = (b.z - b.x) * (b.w - b.y);
    return inter / (aa + ab - inter + 1e-7f);
}

__device__ __forceinline__ float4 decode_one(const float4 a4, const float4 d4) {
    float ah = a4.z - a4.x, aw = a4.w - a4.y;
    float acy = a4.x + 0.5f * ah, acx = a4.y + 0.5f * aw;
    float h = expf(d4.z) * ah, w = expf(d4.w) * aw;
    float cy = d4.x * ah + acy, cx = d4.y * aw + acx;
    float y1 = cy - 0.5f * h, x1 = cx - 0.5f * w;
    return make_float4(y1, x1, y1 + h, x1 + w);
}

__global__ __launch_bounds__(1024)
void roi_bbox_kernel(const float* __restrict__ deltas,
                     const float* __restrict__ labels,
                     const float* __restrict__ anchors,
                     const float* __restrict__ gt,
                     float* __restrict__ out)
{
    __shared__ u64    s_keys[KCAND];     // 32 KB
    __shared__ float4 s_acc[NSEL];       // accepted raw (unclipped) boxes, pop order
    __shared__ float4 s_cbox[2][64];     // double-buffered chunk boxes
    __shared__ unsigned int s_pre[64];   // suppressed-by-accepted flags
    __shared__ unsigned int s_gmlo[64];  // intra-chunk mask lo
    __shared__ unsigned int s_gmhi[64];  // intra-chunk mask hi
    __shared__ int   s_cnt;
    __shared__ int   s_accCount;
    __shared__ float s_merged[NSEL];
    __shared__ int   s_gtbest[NSEL];
    __shared__ float4 s_gt[NGT];
    __shared__ int   s_selidx[64];

    const int b   = blockIdx.x;
    const int tid = threadIdx.x;
    const int lane = tid & 63;
    const float*  sc    = labels + (size_t)b * N_ANCH;
    const float4* anch4 = (const float4*)(anchors + (size_t)b * N_ANCH * 4);
    const float4* del4  = (const float4*)(deltas  + (size_t)b * N_ANCH * 4);
    const float4* gt4   = (const float4*)(gt + (size_t)b * NGT * 4);

    if (tid == 0) { s_cnt = 0; s_accCount = 0; }
    __syncthreads();

    // ---- Phase A: threshold-compact candidates (wave-aggregated push) ----
    for (int i = tid; i < N_ANCH; i += 1024) {
        float sval = sc[i];
        bool pred = (sval > SCORE_THRESH);
        u64 m = __ballot(pred);
        int base = 0;
        if (lane == 0 && m) base = atomicAdd(&s_cnt, __popcll(m));
        base = __shfl(base, 0);
        if (pred) {
            int p = base + __popcll(m & ((1ull << lane) - 1ull));
            if (p < KCAND)
                s_keys[p] = ((u64)__float_as_uint(sval) << 32)
                          | (u64)(0xFFFFFFFFu - (unsigned)i);
        }
    }
    __syncthreads();
    int M = s_cnt; if (M > KCAND) M = KCAND;
    for (int i = tid; i < KCAND; i += 1024) if (i >= M) s_keys[i] = 0ull;
    __syncthreads();

    // ---- bitonic sort, descending (score desc, then index asc) ----
    for (int k = 2; k <= KCAND; k <<= 1) {
        for (int j = k >> 1; j > 0; j >>= 1) {
            #pragma unroll
            for (int ss = 0; ss < KCAND / 1024; ++ss) {
                int i = tid + (ss << 10);
                int l = i ^ j;
                if (l > i) {
                    u64 a = s_keys[i];
                    u64 c = s_keys[l];
                    bool up = ((i & k) == 0);
                    if (up ? (a < c) : (a > c)) { s_keys[i] = c; s_keys[l] = a; }
                }
            }
            __syncthreads();
        }
    }

    // decode chunk 0
    if (tid < 64 && tid < M) {
        u64 key = s_keys[tid];
        int idx = (int)(0xFFFFFFFFu - (unsigned)(key & 0xFFFFFFFFull));
        s_cbox[0][tid] = decode_one(anch4[idx], del4[idx]);
    }
    __syncthreads();

    // ---- Phase B: greedy NMS over sorted candidates, 64-wide chunks ----
    int accCount = 0;
    for (int start = 0; start < M && accCount < NSEL; start += 64) {
        int C = M - start; if (C > 64) C = 64;
        int buf = (start >> 6) & 1;
        if (tid < 64) {
            s_pre[tid]  = (tid < C) ? 0u : 1u;
            s_gmlo[tid] = 0u;
            s_gmhi[tid] = 0u;
        }
        __syncthreads();

        int c = tid & 63;
        int w = tid >> 6;
        if (w == 1) {
            // prefetch-decode next chunk while others compute IoU
            int ni = start + 64 + c;
            if (ni < M) {
                u64 key = s_keys[ni];
                int idx = (int)(0xFFFFFFFFu - (unsigned)(key & 0xFFFFFFFFull));
                s_cbox[buf ^ 1][c] = decode_one(anch4[idx], del4[idx]);
            }
        } else if (c < C) {
            int sidx = (w == 0) ? 0 : (w - 1);   // 15 slices: waves {0,2..15}
            float4 bc = s_cbox[buf][c];
            bool supp = false;
            for (int a = sidx; a < accCount; a += 15)
                supp |= (iou4(s_acc[a], bc) >= 0.5f);
            if (supp) atomicOr(&s_pre[c], 1u);
            unsigned int mlo = 0u, mhi = 0u;
            for (int j = sidx; j < c; j += 15) {
                if (iou4(s_cbox[buf][j], bc) >= 0.5f) {
                    if (j < 32) mlo |= 1u << j; else mhi |= 1u << (j - 32);
                }
            }
            if (mlo) atomicOr(&s_gmlo[c], mlo);
            if (mhi) atomicOr(&s_gmhi[c], mhi);
        }
        __syncthreads();

        // wave-0 resolution: iterate only over alive lanes (each pick == accept)
        if (tid < 64) {
            u64 mymask = ((u64)s_gmhi[tid] << 32) | (u64)s_gmlo[tid];
            bool alive = (tid < C) && (s_pre[tid] == 0u);
            u64 accbits = 0ull;
            u64 done = 0ull;
            int room = NSEL - accCount;
            while (__popcll(accbits) < room) {
                u64 am  = __ballot(alive);
                u64 rem = am & ~done;
                if (!rem) break;
                int l = __ffsll(rem) - 1;
                done = (2ull << l) - 1ull;          // l==63 -> all ones
                accbits |= (1ull << l);
                if ((mymask >> l) & 1ull) alive = false;
            }
            if ((accbits >> tid) & 1ull) {
                int rank = __popcll(accbits & ((1ull << tid) - 1ull));
                s_acc[accCount + rank] = s_cbox[buf][tid];
            }
            if (tid == 0) s_accCount = accCount + __popcll(accbits);
        }
        __syncthreads();
        accCount = s_accCount;
    }

    // ---- Phase C: select_rois ----
    if (tid < NGT) s_gt[tid] = gt4[tid];
    __syncthreads();

    if (tid < NSEL) {
        float4 bx;
        if (tid < accCount) {
            float4 r = s_acc[tid];
            bx = make_float4(clip01(r.x), clip01(r.y), clip01(r.z), clip01(r.w));
        } else bx = make_float4(0.f, 0.f, 0.f, 0.f);
        float aa = (bx.z - bx.x) * (bx.w - bx.y);
        float best = -1e38f; int bi = 0;
        for (int g = 0; g < NGT; ++g) {
            float4 gb = s_gt[g];
            float y1 = fmaxf(bx.x, gb.x);
            float x1 = fmaxf(bx.y, gb.y);
            float y2 = fminf(bx.z, gb.z);
            float x2 = fminf(bx.w, gb.w);
            float ih = fmaxf(y2 - y1, 0.0f);
            float iw = fmaxf(x2 - x1, 0.0f);
            float inter = ih * iw;
            float ab = (gb.z - gb.x) * (gb.w - gb.y);
            float iou = inter / (aa + ab - inter + 1e-7f);
            if (iou > best) { best = iou; bi = g; }   // first-occurrence argmax
        }
        s_merged[tid] = best;
        s_gtbest[tid] = bi;
    }
    __syncthreads();

    // stable top-64 via rank selection: rank = #{j: v_j > v_i || (v_j==v_i && j<i)}
    if (tid < NSEL) {
        float v = s_merged[tid];
        int rank = 0;
        for (int j = 0; j < NSEL; ++j) {
            float u = s_merged[j];
            rank += (u > v) || (u == v && j < tid);
        }
        if (rank < 64) s_selidx[rank] = tid;
    }
    __syncthreads();

    // ---- outputs ----
    float* outIdx = out + (size_t)NBATCH * 128 * 4;   // 8192 box floats first
    if (tid < 256) {
        int r = tid >> 2, cc = tid & 3;
        int i = s_selidx[r];
        float val = 0.0f;
        if (i < accCount) {
            const float* p = (const float*)&s_acc[i];
            val = clip01(p[cc]);
        }
        out[((size_t)b * 128 + r) * 4 + cc] = val;
    } else if (tid < 512) {
        int j = tid - 256;
        out[((size_t)b * 128 + 64) * 4 + j] = 0.0f;   // TOTAL_NEG zero boxes
    } else if (tid < 576) {
        int r = tid - 512;
        outIdx[b * 64 + r] = (float)s_gtbest[s_selidx[r]];
    }
}

extern "C" void kernel_launch(void* const* d_in, const int* in_sizes, int n_in,
                              void* d_out, int out_size, void* d_ws, size_t ws_size,
                              hipStream_t stream) {
    const float* deltas  = (const float*)d_in[0];
    const float* labels  = (const float*)d_in[1];
    const float* anchors = (const float*)d_in[2];
    const float* gt      = (const float*)d_in[3];
    float* out = (float*)d_out;
    roi_bbox_kernel<<<NBATCH, 1024, 0, stream>>>(deltas, labels, anchors, gt, out);
}

// Round 3
// 176.763 us; speedup vs baseline: 1.4507x; 1.2033x over previous
//
#include <hip/hip_runtime.h>
#include <stdint.h>

#define N_ANCH 36864
#define KCAND  4096
#define NBUCK  384
#define NSEL   300
#define NGT    64
#define NBATCH 16
#define SCORE_THRESH 0.908f

typedef unsigned long long u64;

__device__ __forceinline__ float clip01(float v) { return fminf(fmaxf(v, 0.0f), 1.0f); }

// IoU with the exact op order of the reference (a = earlier/selected box)
__device__ __forceinline__ float iou4(const float4 a, const float4 b) {
    float y1 = fmaxf(a.x, b.x);
    float x1 = fmaxf(a.y, b.y);
    float y2 = fminf(a.z, b.z);
    float x2 = fminf(a.w, b.w);
    float ih = fmaxf(y2 - y1, 0.0f);
    float iw = fmaxf(x2 - x1, 0.0f);
    float inter = ih * iw;
    float aa = (a.z - a.x) * (a.w - a.y);
    float ab = (b.z - b.x) * (b.w - b.y);
    return inter / (aa + ab - inter + 1e-7f);
}

__device__ __forceinline__ float4 decode_one(const float4 a4, const float4 d4) {
    float ah = a4.z - a4.x, aw = a4.w - a4.y;
    float acy = a4.x + 0.5f * ah, acx = a4.y + 0.5f * aw;
    float h = expf(d4.z) * ah, w = expf(d4.w) * aw;
    float cy = d4.x * ah + acy, cx = d4.y * aw + acx;
    float y1 = cy - 0.5f * h, x1 = cx - 0.5f * w;
    return make_float4(y1, x1, y1 + h, x1 + w);
}

// scores in (0.908, 1.0) all share exponent 0x7E -> ulp-linear bucket digit,
// ascending digit == descending score. width 4096 ulps -> lambda ~9 per bucket.
__device__ __forceinline__ int bucket_of(float s) {
    unsigned d = (0x3F800000u - __float_as_uint(s)) >> 12;
    return (d < NBUCK) ? (int)d : (NBUCK - 1);
}

__global__ __launch_bounds__(1024)
void roi_bbox_kernel(const float* __restrict__ deltas,
                     const float* __restrict__ labels,
                     const float* __restrict__ anchors,
                     const float* __restrict__ gt,
                     float* __restrict__ out)
{
    __shared__ u64    s_sorted[KCAND];   // 32 KB, bucket-ordered then rank-sorted
    __shared__ int    s_hist[NBUCK];
    __shared__ int    s_cur[NBUCK];
    __shared__ int    s_base[NBUCK + 1];
    __shared__ float4 s_acc[NSEL];       // accepted raw (unclipped) boxes, pop order
    __shared__ float4 s_cbox[2][64];     // double-buffered chunk boxes
    __shared__ unsigned int s_pre[64];
    __shared__ unsigned int s_gmlo[64];
    __shared__ unsigned int s_gmhi[64];
    __shared__ int   s_accCount;
    __shared__ float s_merged[NSEL];
    __shared__ int   s_gtbest[NSEL];
    __shared__ float4 s_gt[NGT];
    __shared__ int   s_selidx[64];

    const int b    = blockIdx.x;
    const int tid  = threadIdx.x;
    const int lane = tid & 63;
    const int wv   = tid >> 6;
    const float*  sc    = labels + (size_t)b * N_ANCH;
    const float4* anch4 = (const float4*)(anchors + (size_t)b * N_ANCH * 4);
    const float4* del4  = (const float4*)(deltas  + (size_t)b * N_ANCH * 4);
    const float4* gt4   = (const float4*)(gt + (size_t)b * NGT * 4);

    if (tid < NBUCK) s_hist[tid] = 0;
    if (tid == 0) s_accCount = 0;
    __syncthreads();

    // ---- Phase A1: bucket histogram ----
    for (int i = tid; i < N_ANCH; i += 1024) {
        float sval = sc[i];
        if (sval > SCORE_THRESH) atomicAdd(&s_hist[bucket_of(sval)], 1);
    }
    __syncthreads();

    // ---- exclusive scan of 384 counts (wave 0: 6 counts/lane + shfl scan) ----
    if (tid < 64) {
        int c[6]; int sum = 0;
        #pragma unroll
        for (int k = 0; k < 6; ++k) { c[k] = s_hist[tid * 6 + k]; sum += c[k]; }
        int inc = sum;
        #pragma unroll
        for (int off = 1; off < 64; off <<= 1) {
            int v = __shfl_up(inc, off);
            if (lane >= off) inc += v;
        }
        int excl = inc - sum;
        #pragma unroll
        for (int k = 0; k < 6; ++k) {
            s_base[tid * 6 + k] = excl;
            s_cur[tid * 6 + k]  = excl;
            excl += c[k];
        }
        if (tid == 63) s_base[NBUCK] = excl;
    }
    __syncthreads();

    // ---- Phase A2: scatter keys into bucket regions (L2-hot reload) ----
    for (int i = tid; i < N_ANCH; i += 1024) {
        float sval = sc[i];
        if (sval > SCORE_THRESH) {
            int pos = atomicAdd(&s_cur[bucket_of(sval)], 1);
            if (pos < KCAND)
                s_sorted[pos] = ((u64)__float_as_uint(sval) << 32)
                              | (u64)(0xFFFFFFFFu - (unsigned)i);
        }
    }
    __syncthreads();

    // ---- per-bucket rank sort (one wave per bucket, no barriers inside) ----
    for (int bk = wv; bk < NBUCK; bk += 16) {
        int lo = s_base[bk], hi = s_base[bk + 1];
        if (lo > KCAND) lo = KCAND;
        if (hi > KCAND) hi = KCAND;
        int n = hi - lo;
        if (n <= 1) continue;
        u64 mykey = (lane < n) ? s_sorted[lo + lane] : 0ull;
        int rank = 0;
        for (int j = 0; j < n; ++j) {          // broadcast reads, conflict-free
            u64 kj = s_sorted[lo + j];
            rank += (kj > mykey);
        }
        if (lane < n) s_sorted[lo + rank] = mykey;  // in-wave: reads precede write
    }
    __syncthreads();

    int M = s_base[NBUCK]; if (M > KCAND) M = KCAND;

    // decode chunk 0
    if (tid < 64 && tid < M) {
        u64 key = s_sorted[tid];
        int idx = (int)(0xFFFFFFFFu - (unsigned)(key & 0xFFFFFFFFull));
        s_cbox[0][tid] = decode_one(anch4[idx], del4[idx]);
    }
    __syncthreads();

    // ---- Phase B: greedy NMS over sorted candidates, 64-wide chunks ----
    int accCount = 0;
    for (int start = 0; start < M && accCount < NSEL; start += 64) {
        int C = M - start; if (C > 64) C = 64;
        int buf = (start >> 6) & 1;
        if (tid < 64) {
            s_pre[tid]  = (tid < C) ? 0u : 1u;
            s_gmlo[tid] = 0u;
            s_gmhi[tid] = 0u;
        }
        __syncthreads();

        int c = tid & 63;
        if (wv == 1) {
            int ni = start + 64 + c;           // prefetch-decode next chunk
            if (ni < M) {
                u64 key = s_sorted[ni];
                int idx = (int)(0xFFFFFFFFu - (unsigned)(key & 0xFFFFFFFFull));
                s_cbox[buf ^ 1][c] = decode_one(anch4[idx], del4[idx]);
            }
        } else if (c < C) {
            int sidx = (wv == 0) ? 0 : (wv - 1);   // 15 slices: waves {0,2..15}
            float4 bc = s_cbox[buf][c];
            bool supp = false;
            for (int a = sidx; a < accCount; a += 15)
                supp |= (iou4(s_acc[a], bc) >= 0.5f);
            if (supp) atomicOr(&s_pre[c], 1u);
            unsigned int mlo = 0u, mhi = 0u;
            for (int j = sidx; j < c; j += 15) {
                if (iou4(s_cbox[buf][j], bc) >= 0.5f) {
                    if (j < 32) mlo |= 1u << j; else mhi |= 1u << (j - 32);
                }
            }
            if (mlo) atomicOr(&s_gmlo[c], mlo);
            if (mhi) atomicOr(&s_gmhi[c], mhi);
        }
        __syncthreads();

        // wave-0 resolution: iterate only over alive lanes (each pick == accept)
        if (tid < 64) {
            u64 mymask = ((u64)s_gmhi[tid] << 32) | (u64)s_gmlo[tid];
            bool alive = (tid < C) && (s_pre[tid] == 0u);
            u64 accbits = 0ull;
            u64 done = 0ull;
            int room = NSEL - accCount;
            while (__popcll(accbits) < room) {
                u64 am  = __ballot(alive);
                u64 rem = am & ~done;
                if (!rem) break;
                int l = __ffsll(rem) - 1;
                done = (2ull << l) - 1ull;
                accbits |= (1ull << l);
                if ((mymask >> l) & 1ull) alive = false;
            }
            if ((accbits >> tid) & 1ull) {
                int rank = __popcll(accbits & ((1ull << tid) - 1ull));
                s_acc[accCount + rank] = s_cbox[buf][tid];
            }
            if (tid == 0) s_accCount = accCount + __popcll(accbits);
        }
        __syncthreads();
        accCount = s_accCount;
    }

    // ---- Phase C: select_rois ----
    if (tid < NGT) s_gt[tid] = gt4[tid];
    __syncthreads();

    if (tid < NSEL) {
        float4 bx;
        if (tid < accCount) {
            float4 r = s_acc[tid];
            bx = make_float4(clip01(r.x), clip01(r.y), clip01(r.z), clip01(r.w));
        } else bx = make_float4(0.f, 0.f, 0.f, 0.f);
        float aa = (bx.z - bx.x) * (bx.w - bx.y);
        float best = -1e38f; int bi = 0;
        for (int g = 0; g < NGT; ++g) {
            float4 gb = s_gt[g];
            float y1 = fmaxf(bx.x, gb.x);
            float x1 = fmaxf(bx.y, gb.y);
            float y2 = fminf(bx.z, gb.z);
            float x2 = fminf(bx.w, gb.w);
            float ih = fmaxf(y2 - y1, 0.0f);
            float iw = fmaxf(x2 - x1, 0.0f);
            float inter = ih * iw;
            float ab = (gb.z - gb.x) * (gb.w - gb.y);
            float iou = inter / (aa + ab - inter + 1e-7f);
            if (iou > best) { best = iou; bi = g; }   // first-occurrence argmax
        }
        s_merged[tid] = best;
        s_gtbest[tid] = bi;
    }
    __syncthreads();

    // stable top-64 via rank selection: rank = #{j: v_j > v_i || (v_j==v_i && j<i)}
    if (tid < NSEL) {
        float v = s_merged[tid];
        int rank = 0;
        for (int j = 0; j < NSEL; ++j) {
            float u = s_merged[j];
            rank += (u > v) || (u == v && j < tid);
        }
        if (rank < 64) s_selidx[rank] = tid;
    }
    __syncthreads();

    // ---- outputs ----
    float* outIdx = out + (size_t)NBATCH * 128 * 4;   // 8192 box floats first
    if (tid < 256) {
        int r = tid >> 2, cc = tid & 3;
        int i = s_selidx[r];
        float val = 0.0f;
        if (i < accCount) {
            const float* p = (const float*)&s_acc[i];
            val = clip01(p[cc]);
        }
        out[((size_t)b * 128 + r) * 4 + cc] = val;
    } else if (tid < 512) {
        int j = tid - 256;
        out[((size_t)b * 128 + 64) * 4 + j] = 0.0f;   // TOTAL_NEG zero boxes
    } else if (tid < 576) {
        int r = tid - 512;
        outIdx[b * 64 + r] = (float)s_gtbest[s_selidx[r]];
    }
}

extern "C" void kernel_launch(void* const* d_in, const int* in_sizes, int n_in,
                              void* d_out, int out_size, void* d_ws, size_t ws_size,
                              hipStream_t stream) {
    const float* deltas  = (const float*)d_in[0];
    const float* labels  = (const float*)d_in[1];
    const float* anchors = (const float*)d_in[2];
    const float* gt      = (const float*)d_in[3];
    float* out = (float*)d_out;
    roi_bbox_kernel<<<NBATCH, 1024, 0, stream>>>(deltas, labels, anchors, gt, out);
}